// Round 8
// baseline (546.714 us; speedup 1.0000x reference)
//
#include <hip/hip_runtime.h>
#include <math.h>

#define N_NODES 50000
#define N_EDGES 800000
#define NEG_SLOPE 0.2f

// ---------- helpers ----------
__device__ __forceinline__ float wred64(float v) {
#pragma unroll
    for (int off = 32; off > 0; off >>= 1) v += __shfl_xor(v, off, 64);
    return v;
}
__device__ __forceinline__ float wmax64(float v) {
#pragma unroll
    for (int off = 32; off > 0; off >>= 1) v = fmaxf(v, __shfl_xor(v, off, 64));
    return v;
}
__device__ __forceinline__ int wredi64(int v) {
#pragma unroll
    for (int off = 32; off > 0; off >>= 1) v += __shfl_xor(v, off, 64);
    return v;
}

// ---------- tiny precompute: ve1[16][2], ve2[16] ----------
__global__ void k_ve(const float* __restrict__ We1, const float* __restrict__ atte1,
                     const float* __restrict__ We2, const float* __restrict__ atte2,
                     float* __restrict__ ve1, float* __restrict__ ve2) {
    int t = threadIdx.x;
    if (t < 32) {
        int k = t >> 1, h = t & 1;
        float s = 0.f;
        for (int c = 0; c < 64; ++c) s = fmaf(We1[k * 128 + h * 64 + c], atte1[h * 64 + c], s);
        ve1[k * 2 + h] = s;
    } else if (t < 48) {
        int k = t - 32;
        float s = 0.f;
        for (int c = 0; c < 64; ++c) s = fmaf(We2[k * 64 + c], atte2[c], s);
        ve2[k] = s;
    }
}

// ---------- conv1 node transform: h1 = x @ W1 (128->128), a_s1/a_d1 ----------
#define GRID1 1536
__global__ __launch_bounds__(128) void k_gemm1(const float* __restrict__ x, const float* __restrict__ W1,
                                               const float* __restrict__ atts, const float* __restrict__ attd,
                                               float* __restrict__ h1, float* __restrict__ a_s,
                                               float* __restrict__ a_d) {
    int j = threadIdx.x;
    int head = j >> 6;
    float wr[128];
#pragma unroll
    for (int k = 0; k < 128; ++k) wr[k] = W1[k * 128 + j];
    float asj = atts[j], adj = attd[j];
    for (int n = blockIdx.x * 2; n < N_NODES; n += GRID1 * 2) {
        const float* xr0 = x + (size_t)n * 128;
        const float* xr1 = xr0 + 128;
        float a0 = 0.f, a1 = 0.f;
#pragma unroll
        for (int k = 0; k < 128; ++k) {
            a0 = fmaf(xr0[k], wr[k], a0);
            a1 = fmaf(xr1[k], wr[k], a1);
        }
        h1[(size_t)n * 128 + j] = a0;
        h1[(size_t)(n + 1) * 128 + j] = a1;
        float ps0 = wred64(a0 * asj), pd0 = wred64(a0 * adj);
        float ps1 = wred64(a1 * asj), pd1 = wred64(a1 * adj);
        if ((j & 63) == 0) {
            a_s[n * 2 + head] = ps0;
            a_d[n * 2 + head] = pd0;
            a_s[(n + 1) * 2 + head] = ps1;
            a_d[(n + 1) * 2 + head] = pd1;
        }
    }
}

// ---------- conv2 node transform: h2 = h2in @ W2 (128->64), a_s2/a_d2 ----------
#define GRID2 3072
__global__ __launch_bounds__(64) void k_gemm2(const float* __restrict__ xin, const float* __restrict__ W,
                                              const float* __restrict__ atts, const float* __restrict__ attd,
                                              float* __restrict__ h2, float* __restrict__ a_s,
                                              float* __restrict__ a_d) {
    int j = threadIdx.x;
    float wr[128];
#pragma unroll
    for (int k = 0; k < 128; ++k) wr[k] = W[k * 64 + j];
    float asj = atts[j], adj = attd[j];
    for (int n = blockIdx.x * 2; n < N_NODES; n += GRID2 * 2) {
        const float* xr0 = xin + (size_t)n * 128;
        const float* xr1 = xr0 + 128;
        float a0 = 0.f, a1 = 0.f;
#pragma unroll
        for (int k = 0; k < 128; ++k) {
            a0 = fmaf(xr0[k], wr[k], a0);
            a1 = fmaf(xr1[k], wr[k], a1);
        }
        h2[(size_t)n * 64 + j] = a0;
        h2[(size_t)(n + 1) * 64 + j] = a1;
        float ps0 = wred64(a0 * asj), pd0 = wred64(a0 * adj);
        float ps1 = wred64(a1 * asj), pd1 = wred64(a1 * adj);
        if (j == 0) {
            a_s[n] = ps0;
            a_d[n] = pd0;
            a_s[n + 1] = ps1;
            a_d[n + 1] = pd1;
        }
    }
}

// ---------- classifier node-side: P1 = hf@Wc1[0:64]+bc1, P2 = hf@Wc1[64:128] ----------
__global__ __launch_bounds__(64) void k_p12(const float* __restrict__ hf, const float* __restrict__ Wc1,
                                            const float* __restrict__ bc1, float* __restrict__ P1,
                                            float* __restrict__ P2) {
    int j = threadIdx.x;
    float wr1[64], wr2[64];
#pragma unroll
    for (int k = 0; k < 64; ++k) {
        wr1[k] = Wc1[k * 64 + j];
        wr2[k] = Wc1[(64 + k) * 64 + j];
    }
    float bj = bc1[j];
    for (int n = blockIdx.x * 2; n < N_NODES; n += GRID2 * 2) {
        const float* xr0 = hf + (size_t)n * 64;
        const float* xr1 = xr0 + 64;
        float a10 = bj, a20 = 0.f, a11 = bj, a21 = 0.f;
#pragma unroll
        for (int k = 0; k < 64; ++k) {
            a10 = fmaf(xr0[k], wr1[k], a10);
            a20 = fmaf(xr0[k], wr2[k], a20);
            a11 = fmaf(xr1[k], wr1[k], a11);
            a21 = fmaf(xr1[k], wr2[k], a21);
        }
        P1[(size_t)n * 64 + j] = a10;
        P2[(size_t)n * 64 + j] = a20;
        P1[(size_t)(n + 1) * 64 + j] = a11;
        P2[(size_t)(n + 1) * 64 + j] = a21;
    }
}

// ---------- edge attention contributions: a_e1[E,2], a_e2[E] (edge order) ----------
__global__ void k_ae(const float* __restrict__ ea, const float* __restrict__ ve1,
                     const float* __restrict__ ve2, float* __restrict__ ae1, float* __restrict__ ae2) {
    int e = blockIdx.x * blockDim.x + threadIdx.x;
    if (e >= N_EDGES) return;
    float s0 = 0.f, s1 = 0.f, s2 = 0.f;
#pragma unroll
    for (int k = 0; k < 16; ++k) {
        float v = ea[e * 16 + k];
        s0 = fmaf(v, ve1[k * 2 + 0], s0);
        s1 = fmaf(v, ve1[k * 2 + 1], s1);
        s2 = fmaf(v, ve2[k], s2);
    }
    ae1[e * 2 + 0] = s0;
    ae1[e * 2 + 1] = s1;
    ae2[e] = s2;
}

// ---------- CSR build: histogram, hierarchical scan, fill ----------
#define SCAN_BLKS ((N_NODES + 255) / 256)  // 196

__global__ void k_hist(const int* __restrict__ dst, int* __restrict__ cnt) {
    int e = blockIdx.x * blockDim.x + threadIdx.x;
    if (e < N_EDGES) atomicAdd(&cnt[dst[e]], 1);
}

// stage 1: per-block (256-chunk) sums of cnt
__global__ __launch_bounds__(256) void k_scan1(const int* __restrict__ cnt, int* __restrict__ bsum) {
    int t = threadIdx.x;
    int idx = blockIdx.x * 256 + t;
    int v = (idx < N_NODES) ? cnt[idx] : 0;
    int w = wredi64(v);
    __shared__ int ws[4];
    if ((t & 63) == 0) ws[t >> 6] = w;
    __syncthreads();
    if (t == 0) bsum[blockIdx.x] = ws[0] + ws[1] + ws[2] + ws[3];
}

// stage 2: exclusive scan of the block sums (in place), single small block
__global__ __launch_bounds__(256) void k_scan2(int* __restrict__ bsum) {
    __shared__ int sh[256];
    int t = threadIdx.x;
    int v = (t < SCAN_BLKS) ? bsum[t] : 0;
    sh[t] = v;
    __syncthreads();
    for (int off = 1; off < 256; off <<= 1) {
        int u = (t >= off) ? sh[t - off] : 0;
        __syncthreads();
        sh[t] += u;
        __syncthreads();
    }
    if (t < SCAN_BLKS) bsum[t] = sh[t] - v;  // exclusive
}

// stage 3: per-chunk LDS scan + block offset -> rp, cursor, rp[N]
__global__ __launch_bounds__(256) void k_scan3(const int* __restrict__ cnt, const int* __restrict__ bsum,
                                               int* __restrict__ rp, int* __restrict__ cursor) {
    __shared__ int sh[256];
    int t = threadIdx.x;
    int idx = blockIdx.x * 256 + t;
    int v = (idx < N_NODES) ? cnt[idx] : 0;
    sh[t] = v;
    __syncthreads();
    for (int off = 1; off < 256; off <<= 1) {
        int u = (t >= off) ? sh[t - off] : 0;
        __syncthreads();
        sh[t] += u;
        __syncthreads();
    }
    if (idx < N_NODES) {
        int excl = bsum[blockIdx.x] + sh[t] - v;
        rp[idx] = excl;
        cursor[idx] = excl;
        if (idx == N_NODES - 1) rp[N_NODES] = excl + v;
    }
}

__global__ void k_fill(const int* __restrict__ dst, int* __restrict__ cursor, int* __restrict__ eord) {
    int e = blockIdx.x * blockDim.x + threadIdx.x;
    if (e < N_EDGES) {
        int p = atomicAdd(&cursor[dst[e]], 1);
        eord[p] = e;
    }
}

// ---------- CSR-ordered edge tables (one-time random gather) ----------
// zo1[i,h] = a_s1[src,h] + a_e1[e,h]   (a_d and leaky applied later, per-dst)
__global__ void k_prep1(const int* __restrict__ eord, const int* __restrict__ src,
                        const float* __restrict__ as1, const float* __restrict__ ae1,
                        int* __restrict__ src_ord, float* __restrict__ zo1) {
    int i = blockIdx.x * blockDim.x + threadIdx.x;
    if (i >= N_EDGES) return;
    int e = eord[i];
    int s = src[e];
    src_ord[i] = s;
    zo1[i * 2 + 0] = as1[s * 2 + 0] + ae1[e * 2 + 0];
    zo1[i * 2 + 1] = as1[s * 2 + 1] + ae1[e * 2 + 1];
}

__global__ void k_prep2(const int* __restrict__ eord, const int* __restrict__ src_ord,
                        const float* __restrict__ as2, const float* __restrict__ ae2,
                        float* __restrict__ zo2) {
    int i = blockIdx.x * blockDim.x + threadIdx.x;
    if (i >= N_EDGES) return;
    zo2[i] = as2[src_ord[i]] + ae2[eord[i]];
}

// ---------- fused per-dst softmax + gather aggregation + bias + ELU ----------
// Block per dst node; streams CSR-ordered zo/src_ord. 3 passes (max, sum, aggregate).
template <int C, int H>
__global__ __launch_bounds__(C) void k_attn_gather(const int* __restrict__ rp, const int* __restrict__ src_ord,
                                                   const float* __restrict__ zo, const float* __restrict__ a_d,
                                                   const float* __restrict__ hfeat, const float* __restrict__ bias,
                                                   float* __restrict__ outp) {
    int n = blockIdx.x;
    int tid = threadIdx.x;
    int beg = rp[n], end = rp[n + 1];
    __shared__ int es[C];
    __shared__ float al[C * H];
    __shared__ float red[2 * H];
    float adn[H];
#pragma unroll
    for (int h = 0; h < H; ++h) adn[h] = a_d[n * H + h];

    // pass 1: segment max (contiguous zo stream)
    float mx[H];
#pragma unroll
    for (int h = 0; h < H; ++h) mx[h] = -3.4e38f;
    for (int i = beg + tid; i < end; i += C) {
#pragma unroll
        for (int h = 0; h < H; ++h) {
            float z = zo[i * H + h] + adn[h];
            z = z > 0.f ? z : NEG_SLOPE * z;
            mx[h] = fmaxf(mx[h], z);
        }
    }
#pragma unroll
    for (int h = 0; h < H; ++h) mx[h] = wmax64(mx[h]);
    if constexpr (C == 128) {
        if ((tid & 63) == 0) {
#pragma unroll
            for (int h = 0; h < H; ++h) red[(tid >> 6) * H + h] = mx[h];
        }
        __syncthreads();
#pragma unroll
        for (int h = 0; h < H; ++h) mx[h] = fmaxf(red[h], red[H + h]);
    }

    // pass 2: exp-sum
    float sm[H];
#pragma unroll
    for (int h = 0; h < H; ++h) sm[h] = 0.f;
    for (int i = beg + tid; i < end; i += C) {
#pragma unroll
        for (int h = 0; h < H; ++h) {
            float z = zo[i * H + h] + adn[h];
            z = z > 0.f ? z : NEG_SLOPE * z;
            sm[h] += __expf(z - mx[h]);
        }
    }
#pragma unroll
    for (int h = 0; h < H; ++h) sm[h] = wred64(sm[h]);
    if constexpr (C == 128) {
        __syncthreads();  // pass1 reads of red done
        if ((tid & 63) == 0) {
#pragma unroll
            for (int h = 0; h < H; ++h) red[(tid >> 6) * H + h] = sm[h];
        }
        __syncthreads();
#pragma unroll
        for (int h = 0; h < H; ++h) sm[h] = red[h] + red[H + h];
    }
    float dinv[H];
#pragma unroll
    for (int h = 0; h < H; ++h) dinv[h] = 1.f / (sm[h] + 1e-16f);

    // pass 3: staged weighted aggregation (src_ord/zo contiguous; hfeat rows random but coalesced)
    float acc = 0.f;
    const int hsel = (H == 2) ? (tid >> 6) : 0;
    for (int base = beg; base < end; base += C) {
        int cnt = min(C, end - base);
        __syncthreads();
        if (tid < cnt) {
            int i = base + tid;
            es[tid] = src_ord[i];
#pragma unroll
            for (int h = 0; h < H; ++h) {
                float z = zo[i * H + h] + adn[h];
                z = z > 0.f ? z : NEG_SLOPE * z;
                al[tid * H + h] = __expf(z - mx[h]) * dinv[h];
            }
        }
        __syncthreads();
#pragma unroll 4
        for (int i = 0; i < cnt; ++i) acc = fmaf(hfeat[(size_t)es[i] * C + tid], al[i * H + hsel], acc);
    }
    float v = acc + bias[tid];
    outp[(size_t)n * C + tid] = v > 0.f ? v : expm1f(v);
}

// ---------- classifier edge-side: warp per dst segment, weights in VGPRs, ILP-4 ----------
__global__ __launch_bounds__(256) void k_final(const int* __restrict__ rp, const int* __restrict__ eord,
                                               const int* __restrict__ src_ord, const float* __restrict__ ea,
                                               const float* __restrict__ P1, const float* __restrict__ P2,
                                               const float* __restrict__ Wc1, const float* __restrict__ Wc2,
                                               const float* __restrict__ bc2, float* __restrict__ out) {
    int tid = threadIdx.x;
    int lane = tid & 63;
    // hoist weights into registers (coalesced 64-wide loads, loop-invariant)
    float wreg[16];
#pragma unroll
    for (int k = 0; k < 16; ++k) wreg[k] = Wc1[128 * 64 + k * 64 + lane];
    float w2 = Wc2[lane];
    float bc = bc2[0];
    int n = blockIdx.x * 4 + (tid >> 6);
    if (n >= N_NODES) return;
    int beg = __builtin_amdgcn_readfirstlane(rp[n]);
    int end = __builtin_amdgcn_readfirstlane(rp[n + 1]);
    if (beg >= end) return;
    float p2 = P2[(size_t)n * 64 + lane];
    int i = beg;
    for (; i + 3 < end; i += 4) {
        int e0 = __builtin_amdgcn_readfirstlane(eord[i]);
        int e1 = __builtin_amdgcn_readfirstlane(eord[i + 1]);
        int e2 = __builtin_amdgcn_readfirstlane(eord[i + 2]);
        int e3 = __builtin_amdgcn_readfirstlane(eord[i + 3]);
        int s0 = __builtin_amdgcn_readfirstlane(src_ord[i]);
        int s1 = __builtin_amdgcn_readfirstlane(src_ord[i + 1]);
        int s2 = __builtin_amdgcn_readfirstlane(src_ord[i + 2]);
        int s3 = __builtin_amdgcn_readfirstlane(src_ord[i + 3]);
        float h0 = p2 + P1[(size_t)s0 * 64 + lane];
        float h1 = p2 + P1[(size_t)s1 * 64 + lane];
        float h2 = p2 + P1[(size_t)s2 * 64 + lane];
        float h3 = p2 + P1[(size_t)s3 * 64 + lane];
        const float* ea0 = ea + (size_t)e0 * 16;
        const float* ea1 = ea + (size_t)e1 * 16;
        const float* ea2 = ea + (size_t)e2 * 16;
        const float* ea3 = ea + (size_t)e3 * 16;
#pragma unroll
        for (int k = 0; k < 16; ++k) {
            float wv = wreg[k];
            h0 = fmaf(ea0[k], wv, h0);
            h1 = fmaf(ea1[k], wv, h1);
            h2 = fmaf(ea2[k], wv, h2);
            h3 = fmaf(ea3[k], wv, h3);
        }
        h0 = fmaxf(h0, 0.f) * w2;
        h1 = fmaxf(h1, 0.f) * w2;
        h2 = fmaxf(h2, 0.f) * w2;
        h3 = fmaxf(h3, 0.f) * w2;
#pragma unroll
        for (int off = 32; off > 0; off >>= 1) {
            h0 += __shfl_xor(h0, off, 64);
            h1 += __shfl_xor(h1, off, 64);
            h2 += __shfl_xor(h2, off, 64);
            h3 += __shfl_xor(h3, off, 64);
        }
        if (lane == 0) {
            out[e0] = h0 + bc;
            out[e1] = h1 + bc;
            out[e2] = h2 + bc;
            out[e3] = h3 + bc;
        }
    }
    for (; i < end; ++i) {
        int e0 = __builtin_amdgcn_readfirstlane(eord[i]);
        int s0 = __builtin_amdgcn_readfirstlane(src_ord[i]);
        float h0 = p2 + P1[(size_t)s0 * 64 + lane];
        const float* ea0 = ea + (size_t)e0 * 16;
#pragma unroll
        for (int k = 0; k < 16; ++k) h0 = fmaf(ea0[k], wreg[k], h0);
        h0 = fmaxf(h0, 0.f);
        float v = wred64(h0 * w2);
        if (lane == 0) out[e0] = v + bc;
    }
}

extern "C" void kernel_launch(void* const* d_in, const int* in_sizes, int n_in,
                              void* d_out, int out_size, void* d_ws, size_t ws_size,
                              hipStream_t stream) {
    const float* x     = (const float*)d_in[0];
    const int*   eidx  = (const int*)d_in[1];
    const float* ea    = (const float*)d_in[2];
    const float* W1    = (const float*)d_in[3];
    const float* atts1 = (const float*)d_in[4];
    const float* attd1 = (const float*)d_in[5];
    const float* We1   = (const float*)d_in[6];
    const float* atte1 = (const float*)d_in[7];
    const float* b1    = (const float*)d_in[8];
    const float* W2    = (const float*)d_in[9];
    const float* atts2 = (const float*)d_in[10];
    const float* attd2 = (const float*)d_in[11];
    const float* We2   = (const float*)d_in[12];
    const float* atte2 = (const float*)d_in[13];
    const float* b2    = (const float*)d_in[14];
    const float* Wc1   = (const float*)d_in[15];
    const float* bc1   = (const float*)d_in[16];
    const float* Wc2   = (const float*)d_in[17];
    const float* bc2   = (const float*)d_in[18];
    const int* srcp = eidx;
    const int* dstp = eidx + N_EDGES;
    float* out = (float*)d_out;

    char* w = (char*)d_ws;
    size_t off = 0;
    auto alloc = [&](size_t bytes) -> void* {
        void* p = w + off;
        off += (bytes + 255) & ~size_t(255);
        return p;
    };

    float* h1   = (float*)alloc(N_NODES * 128 * sizeof(float));  // conv1 features; later h2 / P1 / P2
    float* as1  = (float*)alloc(N_NODES * 2 * sizeof(float));
    float* ad1  = (float*)alloc(N_NODES * 2 * sizeof(float));
    float* ae1  = (float*)alloc(N_EDGES * 2 * sizeof(float));    // dead after k_prep1; reused as zo2
    float* ae2  = (float*)alloc(N_EDGES * sizeof(float));
    float* as2  = (float*)alloc(N_NODES * sizeof(float));
    float* ad2  = (float*)alloc(N_NODES * sizeof(float));
    float* ve1  = (float*)alloc(32 * sizeof(float));
    float* ve2  = (float*)alloc(16 * sizeof(float));
    int*   rp      = (int*)alloc((N_NODES + 1) * sizeof(int));
    int*   eord    = (int*)alloc(N_EDGES * sizeof(int));
    int*   cursor  = (int*)alloc(N_NODES * sizeof(int));
    int*   src_ord = (int*)alloc(N_EDGES * sizeof(int));
    float* zo1     = (float*)alloc(N_EDGES * 2 * sizeof(float));
    float* out1    = (float*)alloc(N_NODES * 128 * sizeof(float));
    float* out2    = (float*)alloc(N_NODES * 64 * sizeof(float));
    int*   bsum    = (int*)alloc(SCAN_BLKS * sizeof(int));

    // aliases (lifetime-disjoint)
    float* h2  = h1;              // [N,64]: gemm2 writes after h1's last read (gather1 pass3)
    float* P1  = h1;              // [N,64]: p12 writes after h2's last read (gather2 pass3)
    float* P2  = h1 + (size_t)N_NODES * 64;
    float* zo2 = ae1;             // [E]: prep2 writes after ae1's last read (prep1)

    // zeroed-every-call region
    char* zstart = w + off;
    int* cnt = (int*)alloc(N_NODES * sizeof(int));
    size_t zbytes = (size_t)((w + off) - zstart);
    hipMemsetAsync(zstart, 0, zbytes, stream);

    const int EB = (N_EDGES + 255) / 256;  // 3125

    // CSR build (shared by both conv layers + classifier)
    k_hist<<<EB, 256, 0, stream>>>(dstp, cnt);
    k_scan1<<<SCAN_BLKS, 256, 0, stream>>>(cnt, bsum);
    k_scan2<<<1, 256, 0, stream>>>(bsum);
    k_scan3<<<SCAN_BLKS, 256, 0, stream>>>(cnt, bsum, rp, cursor);
    k_fill<<<EB, 256, 0, stream>>>(dstp, cursor, eord);

    k_ve<<<1, 64, 0, stream>>>(We1, atte1, We2, atte2, ve1, ve2);
    k_gemm1<<<GRID1, 128, 0, stream>>>(x, W1, atts1, attd1, h1, as1, ad1);
    k_ae<<<EB, 256, 0, stream>>>(ea, ve1, ve2, ae1, ae2);

    // conv1: CSR-ordered tables, then fused softmax+aggregate+bias+ELU
    k_prep1<<<EB, 256, 0, stream>>>(eord, srcp, as1, ae1, src_ord, zo1);
    k_attn_gather<128, 2><<<N_NODES, 128, 0, stream>>>(rp, src_ord, zo1, ad1, h1, b1, out1);

    // conv2
    k_gemm2<<<GRID2, 64, 0, stream>>>(out1, W2, atts2, attd2, h2, as2, ad2);
    k_prep2<<<EB, 256, 0, stream>>>(eord, src_ord, as2, ae2, zo2);
    k_attn_gather<64, 1><<<N_NODES, 64, 0, stream>>>(rp, src_ord, zo2, ad2, h2, b2, out2);

    // edge classifier
    k_p12<<<GRID2, 64, 0, stream>>>(out2, Wc1, bc1, P1, P2);
    k_final<<<(N_NODES + 3) / 4, 256, 0, stream>>>(rp, eord, src_ord, ea, P1, P2, Wc1, Wc2, bc2, out);
}

// Round 9
// 441.730 us; speedup vs baseline: 1.2377x; 1.2377x over previous
//
#include <hip/hip_runtime.h>
#include <math.h>

#define N_NODES 50000
#define N_EDGES 800000
#define NEG_SLOPE 0.2f

// ---------- helpers ----------
__device__ __forceinline__ float wred64(float v) {
#pragma unroll
    for (int off = 32; off > 0; off >>= 1) v += __shfl_xor(v, off, 64);
    return v;
}
__device__ __forceinline__ float wmax64(float v) {
#pragma unroll
    for (int off = 32; off > 0; off >>= 1) v = fmaxf(v, __shfl_xor(v, off, 64));
    return v;
}
__device__ __forceinline__ int wredi64(int v) {
#pragma unroll
    for (int off = 32; off > 0; off >>= 1) v += __shfl_xor(v, off, 64);
    return v;
}

// ---------- tiny precompute: ve1[16][2], ve2[16] ----------
__global__ void k_ve(const float* __restrict__ We1, const float* __restrict__ atte1,
                     const float* __restrict__ We2, const float* __restrict__ atte2,
                     float* __restrict__ ve1, float* __restrict__ ve2) {
    int t = threadIdx.x;
    if (t < 32) {
        int k = t >> 1, h = t & 1;
        float s = 0.f;
        for (int c = 0; c < 64; ++c) s = fmaf(We1[k * 128 + h * 64 + c], atte1[h * 64 + c], s);
        ve1[k * 2 + h] = s;
    } else if (t < 48) {
        int k = t - 32;
        float s = 0.f;
        for (int c = 0; c < 64; ++c) s = fmaf(We2[k * 64 + c], atte2[c], s);
        ve2[k] = s;
    }
}

// ---------- conv1 node transform: h1 = x @ W1 (128->128), a_s1/a_d1 ----------
// W column in 128 VGPRs; 8 node-rows staged in LDS per iter via coalesced float4 loads.
#define GRID1 1536
__global__ __launch_bounds__(128) void k_gemm1(const float* __restrict__ x, const float* __restrict__ W1,
                                               const float* __restrict__ atts, const float* __restrict__ attd,
                                               float* __restrict__ h1, float* __restrict__ a_s,
                                               float* __restrict__ a_d) {
    __shared__ float xs[8][128];
    int j = threadIdx.x;
    int head = j >> 6;
    float wr[128];
#pragma unroll
    for (int k = 0; k < 128; ++k) wr[k] = W1[k * 128 + j];
    float asj = atts[j], adj = attd[j];
    for (int n0 = blockIdx.x * 8; n0 < N_NODES; n0 += GRID1 * 8) {
        __syncthreads();  // protect previous iteration's xs reads
        {
            const float4* src = (const float4*)(x + (size_t)n0 * 128);  // 256 float4 = 8 rows
            float4* dst = (float4*)&xs[0][0];
            dst[j] = src[j];
            dst[j + 128] = src[j + 128];
        }
        __syncthreads();
#pragma unroll 2
        for (int g = 0; g < 8; ++g) {
            int n = n0 + g;
            float a = 0.f;
#pragma unroll
            for (int k = 0; k < 128; ++k) a = fmaf(xs[g][k], wr[k], a);
            h1[(size_t)n * 128 + j] = a;
            float ps = wred64(a * asj), pd = wred64(a * adj);
            if ((j & 63) == 0) {
                a_s[n * 2 + head] = ps;
                a_d[n * 2 + head] = pd;
            }
        }
    }
}

// ---------- conv2 node transform: h2 = h2in @ W2 (128->64), a_s2/a_d2 ----------
#define GRID2 3072
__global__ __launch_bounds__(64) void k_gemm2(const float* __restrict__ xin, const float* __restrict__ W,
                                              const float* __restrict__ atts, const float* __restrict__ attd,
                                              float* __restrict__ h2, float* __restrict__ a_s,
                                              float* __restrict__ a_d) {
    __shared__ float xs[8][128];
    int j = threadIdx.x;
    float wr[128];
#pragma unroll
    for (int k = 0; k < 128; ++k) wr[k] = W[k * 64 + j];
    float asj = atts[j], adj = attd[j];
    for (int n0 = blockIdx.x * 8; n0 < N_NODES; n0 += GRID2 * 8) {
        __syncthreads();
        {
            const float4* src = (const float4*)(xin + (size_t)n0 * 128);  // 256 float4
            float4* dst = (float4*)&xs[0][0];
#pragma unroll
            for (int q = 0; q < 4; ++q) dst[j + 64 * q] = src[j + 64 * q];
        }
        __syncthreads();
#pragma unroll 2
        for (int g = 0; g < 8; ++g) {
            int n = n0 + g;
            float a = 0.f;
#pragma unroll
            for (int k = 0; k < 128; ++k) a = fmaf(xs[g][k], wr[k], a);
            h2[(size_t)n * 64 + j] = a;
            float ps = wred64(a * asj), pd = wred64(a * adj);
            if (j == 0) {
                a_s[n] = ps;
                a_d[n] = pd;
            }
        }
    }
}

// ---------- classifier node-side: P1 = hf@Wc1[0:64]+bc1, P2 = hf@Wc1[64:128] ----------
__global__ __launch_bounds__(64) void k_p12(const float* __restrict__ hf, const float* __restrict__ Wc1,
                                            const float* __restrict__ bc1, float* __restrict__ P1,
                                            float* __restrict__ P2) {
    __shared__ float xs[8][64];
    int j = threadIdx.x;
    float wr1[64], wr2[64];
#pragma unroll
    for (int k = 0; k < 64; ++k) {
        wr1[k] = Wc1[k * 64 + j];
        wr2[k] = Wc1[(64 + k) * 64 + j];
    }
    float bj = bc1[j];
    for (int n0 = blockIdx.x * 8; n0 < N_NODES; n0 += GRID2 * 8) {
        __syncthreads();
        {
            const float4* src = (const float4*)(hf + (size_t)n0 * 64);  // 128 float4 = 8 rows
            float4* dst = (float4*)&xs[0][0];
            dst[j] = src[j];
            dst[j + 64] = src[j + 64];
        }
        __syncthreads();
#pragma unroll 2
        for (int g = 0; g < 8; ++g) {
            int n = n0 + g;
            float a1 = bj, a2 = 0.f;
#pragma unroll
            for (int k = 0; k < 64; ++k) {
                a1 = fmaf(xs[g][k], wr1[k], a1);
                a2 = fmaf(xs[g][k], wr2[k], a2);
            }
            P1[(size_t)n * 64 + j] = a1;
            P2[(size_t)n * 64 + j] = a2;
        }
    }
}

// ---------- edge attention contributions: a_e1[E,2], a_e2[E] (edge order) ----------
__global__ void k_ae(const float* __restrict__ ea, const float* __restrict__ ve1,
                     const float* __restrict__ ve2, float* __restrict__ ae1, float* __restrict__ ae2) {
    int e = blockIdx.x * blockDim.x + threadIdx.x;
    if (e >= N_EDGES) return;
    float s0 = 0.f, s1 = 0.f, s2 = 0.f;
#pragma unroll
    for (int k = 0; k < 16; ++k) {
        float v = ea[e * 16 + k];
        s0 = fmaf(v, ve1[k * 2 + 0], s0);
        s1 = fmaf(v, ve1[k * 2 + 1], s1);
        s2 = fmaf(v, ve2[k], s2);
    }
    ae1[e * 2 + 0] = s0;
    ae1[e * 2 + 1] = s1;
    ae2[e] = s2;
}

// ---------- CSR build: histogram, hierarchical scan, fill ----------
#define SCAN_BLKS ((N_NODES + 255) / 256)  // 196

__global__ void k_hist(const int* __restrict__ dst, int* __restrict__ cnt) {
    int e = blockIdx.x * blockDim.x + threadIdx.x;
    if (e < N_EDGES) atomicAdd(&cnt[dst[e]], 1);
}

// stage 1: per-block (256-chunk) sums of cnt
__global__ __launch_bounds__(256) void k_scan1(const int* __restrict__ cnt, int* __restrict__ bsum) {
    int t = threadIdx.x;
    int idx = blockIdx.x * 256 + t;
    int v = (idx < N_NODES) ? cnt[idx] : 0;
    int w = wredi64(v);
    __shared__ int ws[4];
    if ((t & 63) == 0) ws[t >> 6] = w;
    __syncthreads();
    if (t == 0) bsum[blockIdx.x] = ws[0] + ws[1] + ws[2] + ws[3];
}

// stage 2: exclusive scan of the block sums (in place), single small block
__global__ __launch_bounds__(256) void k_scan2(int* __restrict__ bsum) {
    __shared__ int sh[256];
    int t = threadIdx.x;
    int v = (t < SCAN_BLKS) ? bsum[t] : 0;
    sh[t] = v;
    __syncthreads();
    for (int off = 1; off < 256; off <<= 1) {
        int u = (t >= off) ? sh[t - off] : 0;
        __syncthreads();
        sh[t] += u;
        __syncthreads();
    }
    if (t < SCAN_BLKS) bsum[t] = sh[t] - v;  // exclusive
}

// stage 3: per-chunk LDS scan + block offset -> rp, cursor, rp[N]
__global__ __launch_bounds__(256) void k_scan3(const int* __restrict__ cnt, const int* __restrict__ bsum,
                                               int* __restrict__ rp, int* __restrict__ cursor) {
    __shared__ int sh[256];
    int t = threadIdx.x;
    int idx = blockIdx.x * 256 + t;
    int v = (idx < N_NODES) ? cnt[idx] : 0;
    sh[t] = v;
    __syncthreads();
    for (int off = 1; off < 256; off <<= 1) {
        int u = (t >= off) ? sh[t - off] : 0;
        __syncthreads();
        sh[t] += u;
        __syncthreads();
    }
    if (idx < N_NODES) {
        int excl = bsum[blockIdx.x] + sh[t] - v;
        rp[idx] = excl;
        cursor[idx] = excl;
        if (idx == N_NODES - 1) rp[N_NODES] = excl + v;
    }
}

__global__ void k_fill(const int* __restrict__ dst, int* __restrict__ cursor, int* __restrict__ eord) {
    int e = blockIdx.x * blockDim.x + threadIdx.x;
    if (e < N_EDGES) {
        int p = atomicAdd(&cursor[dst[e]], 1);
        eord[p] = e;
    }
}

// ---------- CSR-ordered edge tables (one-time random gather) ----------
// zo1[i,h] = a_s1[src,h] + a_e1[e,h]   (a_d and leaky applied later, per-dst)
__global__ void k_prep1(const int* __restrict__ eord, const int* __restrict__ src,
                        const float* __restrict__ as1, const float* __restrict__ ae1,
                        int* __restrict__ src_ord, float* __restrict__ zo1) {
    int i = blockIdx.x * blockDim.x + threadIdx.x;
    if (i >= N_EDGES) return;
    int e = eord[i];
    int s = src[e];
    src_ord[i] = s;
    zo1[i * 2 + 0] = as1[s * 2 + 0] + ae1[e * 2 + 0];
    zo1[i * 2 + 1] = as1[s * 2 + 1] + ae1[e * 2 + 1];
}

__global__ void k_prep2(const int* __restrict__ eord, const int* __restrict__ src_ord,
                        const float* __restrict__ as2, const float* __restrict__ ae2,
                        float* __restrict__ zo2) {
    int i = blockIdx.x * blockDim.x + threadIdx.x;
    if (i >= N_EDGES) return;
    zo2[i] = as2[src_ord[i]] + ae2[eord[i]];
}

// ---------- fused per-dst softmax + gather aggregation + bias + ELU ----------
// Block per dst node; streams CSR-ordered zo/src_ord. 3 passes (max, sum, aggregate).
template <int C, int H>
__global__ __launch_bounds__(C) void k_attn_gather(const int* __restrict__ rp, const int* __restrict__ src_ord,
                                                   const float* __restrict__ zo, const float* __restrict__ a_d,
                                                   const float* __restrict__ hfeat, const float* __restrict__ bias,
                                                   float* __restrict__ outp) {
    int n = blockIdx.x;
    int tid = threadIdx.x;
    int beg = rp[n], end = rp[n + 1];
    __shared__ int es[C];
    __shared__ float al[C * H];
    __shared__ float red[2 * H];
    float adn[H];
#pragma unroll
    for (int h = 0; h < H; ++h) adn[h] = a_d[n * H + h];

    // pass 1: segment max (contiguous zo stream)
    float mx[H];
#pragma unroll
    for (int h = 0; h < H; ++h) mx[h] = -3.4e38f;
    for (int i = beg + tid; i < end; i += C) {
#pragma unroll
        for (int h = 0; h < H; ++h) {
            float z = zo[i * H + h] + adn[h];
            z = z > 0.f ? z : NEG_SLOPE * z;
            mx[h] = fmaxf(mx[h], z);
        }
    }
#pragma unroll
    for (int h = 0; h < H; ++h) mx[h] = wmax64(mx[h]);
    if constexpr (C == 128) {
        if ((tid & 63) == 0) {
#pragma unroll
            for (int h = 0; h < H; ++h) red[(tid >> 6) * H + h] = mx[h];
        }
        __syncthreads();
#pragma unroll
        for (int h = 0; h < H; ++h) mx[h] = fmaxf(red[h], red[H + h]);
    }

    // pass 2: exp-sum
    float sm[H];
#pragma unroll
    for (int h = 0; h < H; ++h) sm[h] = 0.f;
    for (int i = beg + tid; i < end; i += C) {
#pragma unroll
        for (int h = 0; h < H; ++h) {
            float z = zo[i * H + h] + adn[h];
            z = z > 0.f ? z : NEG_SLOPE * z;
            sm[h] += __expf(z - mx[h]);
        }
    }
#pragma unroll
    for (int h = 0; h < H; ++h) sm[h] = wred64(sm[h]);
    if constexpr (C == 128) {
        __syncthreads();  // pass1 reads of red done
        if ((tid & 63) == 0) {
#pragma unroll
            for (int h = 0; h < H; ++h) red[(tid >> 6) * H + h] = sm[h];
        }
        __syncthreads();
#pragma unroll
        for (int h = 0; h < H; ++h) sm[h] = red[h] + red[H + h];
    }
    float dinv[H];
#pragma unroll
    for (int h = 0; h < H; ++h) dinv[h] = 1.f / (sm[h] + 1e-16f);

    // pass 3: staged weighted aggregation (src_ord/zo contiguous; hfeat rows random but coalesced)
    float acc = 0.f;
    const int hsel = (H == 2) ? (tid >> 6) : 0;
    for (int base = beg; base < end; base += C) {
        int cnt = min(C, end - base);
        __syncthreads();
        if (tid < cnt) {
            int i = base + tid;
            es[tid] = src_ord[i];
#pragma unroll
            for (int h = 0; h < H; ++h) {
                float z = zo[i * H + h] + adn[h];
                z = z > 0.f ? z : NEG_SLOPE * z;
                al[tid * H + h] = __expf(z - mx[h]) * dinv[h];
            }
        }
        __syncthreads();
#pragma unroll 4
        for (int i = 0; i < cnt; ++i) acc = fmaf(hfeat[(size_t)es[i] * C + tid], al[i * H + hsel], acc);
    }
    float v = acc + bias[tid];
    outp[(size_t)n * C + tid] = v > 0.f ? v : expm1f(v);
}

// ---------- classifier edge-side: warp per dst segment, weights in VGPRs, ILP-4 ----------
__global__ __launch_bounds__(256) void k_final(const int* __restrict__ rp, const int* __restrict__ eord,
                                               const int* __restrict__ src_ord, const float* __restrict__ ea,
                                               const float* __restrict__ P1, const float* __restrict__ P2,
                                               const float* __restrict__ Wc1, const float* __restrict__ Wc2,
                                               const float* __restrict__ bc2, float* __restrict__ out) {
    int tid = threadIdx.x;
    int lane = tid & 63;
    // hoist weights into registers (coalesced 64-wide loads, loop-invariant)
    float wreg[16];
#pragma unroll
    for (int k = 0; k < 16; ++k) wreg[k] = Wc1[128 * 64 + k * 64 + lane];
    float w2 = Wc2[lane];
    float bc = bc2[0];
    int n = blockIdx.x * 4 + (tid >> 6);
    if (n >= N_NODES) return;
    int beg = __builtin_amdgcn_readfirstlane(rp[n]);
    int end = __builtin_amdgcn_readfirstlane(rp[n + 1]);
    if (beg >= end) return;
    float p2 = P2[(size_t)n * 64 + lane];
    int i = beg;
    for (; i + 3 < end; i += 4) {
        int e0 = __builtin_amdgcn_readfirstlane(eord[i]);
        int e1 = __builtin_amdgcn_readfirstlane(eord[i + 1]);
        int e2 = __builtin_amdgcn_readfirstlane(eord[i + 2]);
        int e3 = __builtin_amdgcn_readfirstlane(eord[i + 3]);
        int s0 = __builtin_amdgcn_readfirstlane(src_ord[i]);
        int s1 = __builtin_amdgcn_readfirstlane(src_ord[i + 1]);
        int s2 = __builtin_amdgcn_readfirstlane(src_ord[i + 2]);
        int s3 = __builtin_amdgcn_readfirstlane(src_ord[i + 3]);
        float h0 = p2 + P1[(size_t)s0 * 64 + lane];
        float h1 = p2 + P1[(size_t)s1 * 64 + lane];
        float h2 = p2 + P1[(size_t)s2 * 64 + lane];
        float h3 = p2 + P1[(size_t)s3 * 64 + lane];
        const float* ea0 = ea + (size_t)e0 * 16;
        const float* ea1 = ea + (size_t)e1 * 16;
        const float* ea2 = ea + (size_t)e2 * 16;
        const float* ea3 = ea + (size_t)e3 * 16;
#pragma unroll
        for (int k = 0; k < 16; ++k) {
            float wv = wreg[k];
            h0 = fmaf(ea0[k], wv, h0);
            h1 = fmaf(ea1[k], wv, h1);
            h2 = fmaf(ea2[k], wv, h2);
            h3 = fmaf(ea3[k], wv, h3);
        }
        h0 = fmaxf(h0, 0.f) * w2;
        h1 = fmaxf(h1, 0.f) * w2;
        h2 = fmaxf(h2, 0.f) * w2;
        h3 = fmaxf(h3, 0.f) * w2;
#pragma unroll
        for (int off = 32; off > 0; off >>= 1) {
            h0 += __shfl_xor(h0, off, 64);
            h1 += __shfl_xor(h1, off, 64);
            h2 += __shfl_xor(h2, off, 64);
            h3 += __shfl_xor(h3, off, 64);
        }
        if (lane == 0) {
            out[e0] = h0 + bc;
            out[e1] = h1 + bc;
            out[e2] = h2 + bc;
            out[e3] = h3 + bc;
        }
    }
    for (; i < end; ++i) {
        int e0 = __builtin_amdgcn_readfirstlane(eord[i]);
        int s0 = __builtin_amdgcn_readfirstlane(src_ord[i]);
        float h0 = p2 + P1[(size_t)s0 * 64 + lane];
        const float* ea0 = ea + (size_t)e0 * 16;
#pragma unroll
        for (int k = 0; k < 16; ++k) h0 = fmaf(ea0[k], wreg[k], h0);
        h0 = fmaxf(h0, 0.f);
        float v = wred64(h0 * w2);
        if (lane == 0) out[e0] = v + bc;
    }
}

extern "C" void kernel_launch(void* const* d_in, const int* in_sizes, int n_in,
                              void* d_out, int out_size, void* d_ws, size_t ws_size,
                              hipStream_t stream) {
    const float* x     = (const float*)d_in[0];
    const int*   eidx  = (const int*)d_in[1];
    const float* ea    = (const float*)d_in[2];
    const float* W1    = (const float*)d_in[3];
    const float* atts1 = (const float*)d_in[4];
    const float* attd1 = (const float*)d_in[5];
    const float* We1   = (const float*)d_in[6];
    const float* atte1 = (const float*)d_in[7];
    const float* b1    = (const float*)d_in[8];
    const float* W2    = (const float*)d_in[9];
    const float* atts2 = (const float*)d_in[10];
    const float* attd2 = (const float*)d_in[11];
    const float* We2   = (const float*)d_in[12];
    const float* atte2 = (const float*)d_in[13];
    const float* b2    = (const float*)d_in[14];
    const float* Wc1   = (const float*)d_in[15];
    const float* bc1   = (const float*)d_in[16];
    const float* Wc2   = (const float*)d_in[17];
    const float* bc2   = (const float*)d_in[18];
    const int* srcp = eidx;
    const int* dstp = eidx + N_EDGES;
    float* out = (float*)d_out;

    char* w = (char*)d_ws;
    size_t off = 0;
    auto alloc = [&](size_t bytes) -> void* {
        void* p = w + off;
        off += (bytes + 255) & ~size_t(255);
        return p;
    };

    float* h1   = (float*)alloc(N_NODES * 128 * sizeof(float));  // conv1 features; later h2 / P1 / P2
    float* as1  = (float*)alloc(N_NODES * 2 * sizeof(float));
    float* ad1  = (float*)alloc(N_NODES * 2 * sizeof(float));
    float* ae1  = (float*)alloc(N_EDGES * 2 * sizeof(float));    // dead after k_prep1; reused as zo2
    float* ae2  = (float*)alloc(N_EDGES * sizeof(float));
    float* as2  = (float*)alloc(N_NODES * sizeof(float));
    float* ad2  = (float*)alloc(N_NODES * sizeof(float));
    float* ve1  = (float*)alloc(32 * sizeof(float));
    float* ve2  = (float*)alloc(16 * sizeof(float));
    int*   rp      = (int*)alloc((N_NODES + 1) * sizeof(int));
    int*   eord    = (int*)alloc(N_EDGES * sizeof(int));
    int*   cursor  = (int*)alloc(N_NODES * sizeof(int));
    int*   src_ord = (int*)alloc(N_EDGES * sizeof(int));
    float* zo1     = (float*)alloc(N_EDGES * 2 * sizeof(float));
    float* out1    = (float*)alloc(N_NODES * 128 * sizeof(float));
    float* out2    = (float*)alloc(N_NODES * 64 * sizeof(float));
    int*   bsum    = (int*)alloc(SCAN_BLKS * sizeof(int));

    // aliases (lifetime-disjoint)
    float* h2  = h1;              // [N,64]: gemm2 writes after h1's last read (gather1 pass3)
    float* P1  = h1;              // [N,64]: p12 writes after h2's last read (gather2 pass3)
    float* P2  = h1 + (size_t)N_NODES * 64;
    float* zo2 = ae1;             // [E]: prep2 writes after ae1's last read (prep1)

    // zeroed-every-call region
    char* zstart = w + off;
    int* cnt = (int*)alloc(N_NODES * sizeof(int));
    size_t zbytes = (size_t)((w + off) - zstart);
    hipMemsetAsync(zstart, 0, zbytes, stream);

    const int EB = (N_EDGES + 255) / 256;  // 3125

    // CSR build (shared by both conv layers + classifier)
    k_hist<<<EB, 256, 0, stream>>>(dstp, cnt);
    k_scan1<<<SCAN_BLKS, 256, 0, stream>>>(cnt, bsum);
    k_scan2<<<1, 256, 0, stream>>>(bsum);
    k_scan3<<<SCAN_BLKS, 256, 0, stream>>>(cnt, bsum, rp, cursor);
    k_fill<<<EB, 256, 0, stream>>>(dstp, cursor, eord);

    k_ve<<<1, 64, 0, stream>>>(We1, atte1, We2, atte2, ve1, ve2);
    k_gemm1<<<GRID1, 128, 0, stream>>>(x, W1, atts1, attd1, h1, as1, ad1);
    k_ae<<<EB, 256, 0, stream>>>(ea, ve1, ve2, ae1, ae2);

    // conv1: CSR-ordered tables, then fused softmax+aggregate+bias+ELU
    k_prep1<<<EB, 256, 0, stream>>>(eord, srcp, as1, ae1, src_ord, zo1);
    k_attn_gather<128, 2><<<N_NODES, 128, 0, stream>>>(rp, src_ord, zo1, ad1, h1, b1, out1);

    // conv2
    k_gemm2<<<GRID2, 64, 0, stream>>>(out1, W2, atts2, attd2, h2, as2, ad2);
    k_prep2<<<EB, 256, 0, stream>>>(eord, src_ord, as2, ae2, zo2);
    k_attn_gather<64, 1><<<N_NODES, 64, 0, stream>>>(rp, src_ord, zo2, ad2, h2, b2, out2);

    // edge classifier
    k_p12<<<GRID2, 64, 0, stream>>>(out2, Wc1, bc1, P1, P2);
    k_final<<<(N_NODES + 3) / 4, 256, 0, stream>>>(rp, eord, src_ord, ea, P1, P2, Wc1, Wc2, bc2, out);
}